// Round 3
// baseline (85.085 us; speedup 1.0000x reference)
//
#include <hip/hip_runtime.h>

#define D 128
#define CHUNK 16
#define MAX_TYPES 1024
#define MAX_B 8192
#define GRID_MAIN 1536
#define MARGIN 1.0f

// ws layout (int units)
#define WS_NITEMS 2048
#define WS_ORDER  4096
#define WS_ITEMS  16384
#define WS_NEEDED ((size_t)(24576 * 4))

// ---------------- fused grouping kernel (single block, 1024 thr) ----------------

__global__ __launch_bounds__(1024) void group_kernel(
    const int* __restrict__ type_r, int* __restrict__ ws,
    float* __restrict__ out, int B, int ntype)
{
    __shared__ int hist[MAX_TYPES];
    __shared__ int a[MAX_TYPES];
    __shared__ int typec[MAX_B];
    const int tid = threadIdx.x;
    if (tid == 0) out[0] = 0.0f;
    hist[tid] = 0;
    __syncthreads();
    for (int i = tid; i < B; i += 1024) {
        const int t = type_r[i];
        typec[i] = t;
        atomicAdd(&hist[t], 1);
    }
    __syncthreads();
    const int c = (tid < ntype) ? hist[tid] : 0;
    a[tid] = c;
    __syncthreads();
    int v = c;
    #pragma unroll
    for (int off = 1; off < 1024; off <<= 1) {
        const int add = (tid >= off) ? a[tid - off] : 0;
        __syncthreads();
        v += add;
        a[tid] = v;
        __syncthreads();
    }
    const int excl = v - c;
    hist[tid] = excl;                    // becomes scatter cursor
    // scan #2: item counts
    const int ic = (c + CHUNK - 1) / CHUNK;
    a[tid] = ic;
    __syncthreads();
    int iv = ic;
    #pragma unroll
    for (int off = 1; off < 1024; off <<= 1) {
        const int add = (tid >= off) ? a[tid - off] : 0;
        __syncthreads();
        iv += add;
        a[tid] = iv;
        __syncthreads();
    }
    const int iexcl = iv - ic;
    if (tid < ntype) {
        int4* items = (int4*)(ws + WS_ITEMS);
        for (int i = 0; i < ic; ++i)
            items[iexcl + i] = make_int4(tid, excl + i * CHUNK, min(CHUNK, c - i * CHUNK), 0);
    }
    if (tid == 1023) ws[WS_NITEMS] = iv;
    __syncthreads();
    for (int i = tid; i < B; i += 1024) {
        const int p = atomicAdd(&hist[typec[i]], 1);
        ws[WS_ORDER + p] = i;
    }
}

// ---------------- main kernel ----------------
// 256 thr: thread (cq = tid&31, rb = tid>>5) owns T[16 rows][4 cols] as float4.

__global__ __launch_bounds__(256, 4) void transr_main(
    const float* __restrict__ ent,
    const float* __restrict__ rel,
    const float* __restrict__ tmat,
    const int* __restrict__ pos_h,
    const int* __restrict__ pos_t,
    const int* __restrict__ pos_r,
    const int* __restrict__ neg_h,
    const int* __restrict__ neg_t,
    const int* __restrict__ neg_r,
    const int* __restrict__ ws,
    float* __restrict__ out,
    float inv_B)
{
    const int nit = ws[WS_NITEMS];
    if (blockIdx.x >= nit) return;
    const int4 item = ((const int4*)(ws + WS_ITEMS))[blockIdx.x];
    const int type  = item.x;
    const int start = item.y;
    const int cnt   = item.z;

    const int tid  = threadIdx.x;
    const int cq   = tid & 31;
    const int rb   = tid >> 5;
    const int lane = tid & 63;
    const int w    = tid >> 6;

    __shared__ float4 vbuf[2][D];          // {ph,pt,nh,nt} per dim
    __shared__ float  relP[2][D], relN[2][D];
    __shared__ float  pacc[4][8][D];       // [role][rb][col]
    __shared__ float  sred[16];

    // T panel into registers: 16 x float4, coalesced 16B/lane
    float4 t4[16];
    {
        const float* Tp = tmat + (size_t)type * (D * D) + (size_t)(rb * 16) * D + cq * 4;
        #pragma unroll
        for (int rr = 0; rr < 16; ++rr)
            t4[rr] = *(const float4*)(Tp + rr * D);
    }

    const int* order = ws + WS_ORDER;

    // indices for sample 0
    int i_s = order[start];
    int gih = pos_h[i_s], git = pos_t[i_s], ginh = neg_h[i_s], gint = neg_t[i_s];
    int gipr = pos_r[i_s], ginr = neg_r[i_s];

    float4 rv = make_float4(0.f, 0.f, 0.f, 0.f);
    float rp = 0.f, rn = 0.f;
    // gather rows for sample 0
    if (tid < 128) {
        rv.x = ent[(size_t)gih  * D + tid];
        rv.y = ent[(size_t)git  * D + tid];
        rv.z = ent[(size_t)ginh * D + tid];
        rv.w = ent[(size_t)gint * D + tid];
    } else {
        const int t2 = tid - 128;
        rp = rel[(size_t)gipr * D + t2];
        rn = rel[(size_t)ginr * D + t2];
    }
    // indices for sample 1
    if (cnt > 1) {
        i_s = order[start + 1];
        gih = pos_h[i_s]; git = pos_t[i_s]; ginh = neg_h[i_s]; gint = neg_t[i_s];
        gipr = pos_r[i_s]; ginr = neg_r[i_s];
    }

    int cur = 0;
    float loss = 0.f;

    for (int j = 0; j < cnt; ++j) {
        // commit sample j
        if (tid < 128) vbuf[cur][tid] = rv;
        else { relP[cur][tid - 128] = rp; relN[cur][tid - 128] = rn; }

        // issue row gathers for sample j+1 (indices prefetched last iter)
        if (j + 1 < cnt) {
            if (tid < 128) {
                rv.x = ent[(size_t)gih  * D + tid];
                rv.y = ent[(size_t)git  * D + tid];
                rv.z = ent[(size_t)ginh * D + tid];
                rv.w = ent[(size_t)gint * D + tid];
            } else {
                const int t2 = tid - 128;
                rp = rel[(size_t)gipr * D + t2];
                rn = rel[(size_t)ginr * D + t2];
            }
        }
        // prefetch indices for sample j+2
        if (j + 2 < cnt) {
            i_s = order[start + j + 2];
            gih = pos_h[i_s]; git = pos_t[i_s]; ginh = neg_h[i_s]; gint = neg_t[i_s];
            gipr = pos_r[i_s]; ginr = neg_r[i_s];
        }
        __syncthreads();   // B1: vbuf[cur]/rel[cur] visible

        float4 a0 = make_float4(0.f,0.f,0.f,0.f);
        float4 a1 = a0, a2 = a0, a3 = a0;
        #pragma unroll
        for (int rr = 0; rr < 16; ++rr) {
            const float4 vv = vbuf[cur][rb * 16 + rr];   // broadcast per half-wave
            const float4 t  = t4[rr];
            a0.x = fmaf(vv.x, t.x, a0.x); a0.y = fmaf(vv.x, t.y, a0.y);
            a0.z = fmaf(vv.x, t.z, a0.z); a0.w = fmaf(vv.x, t.w, a0.w);
            a1.x = fmaf(vv.y, t.x, a1.x); a1.y = fmaf(vv.y, t.y, a1.y);
            a1.z = fmaf(vv.y, t.z, a1.z); a1.w = fmaf(vv.y, t.w, a1.w);
            a2.x = fmaf(vv.z, t.x, a2.x); a2.y = fmaf(vv.z, t.y, a2.y);
            a2.z = fmaf(vv.z, t.z, a2.z); a2.w = fmaf(vv.z, t.w, a2.w);
            a3.x = fmaf(vv.w, t.x, a3.x); a3.y = fmaf(vv.w, t.y, a3.y);
            a3.z = fmaf(vv.w, t.z, a3.z); a3.w = fmaf(vv.w, t.w, a3.w);
        }
        *(float4*)&pacc[0][rb][cq * 4] = a0;   // conflict-free: contiguous 512B per half-wave
        *(float4*)&pacc[1][rb][cq * 4] = a1;
        *(float4*)&pacc[2][rb][cq * 4] = a2;
        *(float4*)&pacc[3][rb][cq * 4] = a3;
        __syncthreads();   // B2: pacc visible

        float hph=0.f, hpt=0.f, hnh=0.f, hnt=0.f, prr=0.f, nrr=0.f;
        if (tid < 128) {
            #pragma unroll
            for (int r8 = 0; r8 < 8; ++r8) {
                hph += pacc[0][r8][tid];
                hpt += pacc[1][r8][tid];
                hnh += pacc[2][r8][tid];
                hnt += pacc[3][r8][tid];
            }
            prr = relP[cur][tid];
            nrr = relN[cur][tid];
            float s0 = hph*hph, s1 = hpt*hpt, s2 = hnh*hnh, s3 = hnt*hnt;
            float s4 = prr*prr, s5 = nrr*nrr;
            #pragma unroll
            for (int m = 1; m < 64; m <<= 1) {
                s0 += __shfl_xor(s0, m); s1 += __shfl_xor(s1, m);
                s2 += __shfl_xor(s2, m); s3 += __shfl_xor(s3, m);
                s4 += __shfl_xor(s4, m); s5 += __shfl_xor(s5, m);
            }
            if (lane == 0) {
                sred[w*6+0] = s0; sred[w*6+1] = s1; sred[w*6+2] = s2;
                sred[w*6+3] = s3; sred[w*6+4] = s4; sred[w*6+5] = s5;
            }
        }
        __syncthreads();   // B3: partial square-sums visible

        if (tid < 128) {
            const float iph = rsqrtf(sred[0] + sred[6]  + 1e-12f);
            const float ipt = rsqrtf(sred[1] + sred[7]  + 1e-12f);
            const float inh = rsqrtf(sred[2] + sred[8]  + 1e-12f);
            const float itn = rsqrtf(sred[3] + sred[9]  + 1e-12f);
            const float ipr = rsqrtf(sred[4] + sred[10] + 1e-12f);
            const float inr = rsqrtf(sred[5] + sred[11] + 1e-12f);
            float pterm = fabsf(hph * iph + prr * ipr - hpt * ipt);
            float nterm = fabsf(hnh * inh + nrr * inr - hnt * itn);
            #pragma unroll
            for (int m = 1; m < 64; m <<= 1) {
                pterm += __shfl_xor(pterm, m);
                nterm += __shfl_xor(nterm, m);
            }
            if (lane == 0) { sred[12 + w] = pterm; sred[14 + w] = nterm; }
        }
        __syncthreads();   // B4: score partials visible

        if (tid == 0)
            loss += fmaxf(sred[12] + sred[13] - sred[14] - sred[15] + MARGIN, 0.f);
        cur ^= 1;
    }

    if (tid == 0) atomicAdd(out, loss * inv_B);
}

// ---------------- fallback (round-1 per-sample kernel) ----------------

__global__ __launch_bounds__(128) void transr_fallback(
    const float* __restrict__ ent, const float* __restrict__ rel,
    const float* __restrict__ tmat,
    const int* __restrict__ pos_h, const int* __restrict__ pos_t,
    const int* __restrict__ pos_r, const int* __restrict__ pos_type_r,
    const int* __restrict__ neg_h, const int* __restrict__ neg_t,
    const int* __restrict__ neg_r, float* __restrict__ out, int B)
{
    const int b = blockIdx.x;
    const int r = threadIdx.x;
    const int lane = r & 63;
    const int wid = r >> 6;
    __shared__ float4 vcomb[D];
    __shared__ float sred[16];
    const float* ph = ent + (size_t)pos_h[b] * D;
    const float* pt = ent + (size_t)pos_t[b] * D;
    const float* nh = ent + (size_t)neg_h[b] * D;
    const float* nt = ent + (size_t)neg_t[b] * D;
    vcomb[r] = make_float4(ph[r], pt[r], nh[r], nt[r]);
    const float prr = rel[(size_t)pos_r[b] * D + r];
    const float nrr = rel[(size_t)neg_r[b] * D + r];
    __syncthreads();
    const float* __restrict__ T = tmat + (size_t)pos_type_r[b] * (D * D);
    float aph = 0.f, apt = 0.f, anh = 0.f, ant = 0.f;
    #pragma unroll 8
    for (int d = 0; d < D; ++d) {
        const float t = T[d * D + r];
        const float4 v = vcomb[d];
        aph = fmaf(v.x, t, aph); apt = fmaf(v.y, t, apt);
        anh = fmaf(v.z, t, anh); ant = fmaf(v.w, t, ant);
    }
    float s0 = aph*aph, s1 = apt*apt, s2 = anh*anh, s3 = ant*ant;
    float s4 = prr*prr, s5 = nrr*nrr;
    #pragma unroll
    for (int off = 32; off; off >>= 1) {
        s0 += __shfl_xor(s0, off); s1 += __shfl_xor(s1, off);
        s2 += __shfl_xor(s2, off); s3 += __shfl_xor(s3, off);
        s4 += __shfl_xor(s4, off); s5 += __shfl_xor(s5, off);
    }
    if (lane == 0) {
        sred[wid*8+0]=s0; sred[wid*8+1]=s1; sred[wid*8+2]=s2;
        sred[wid*8+3]=s3; sred[wid*8+4]=s4; sred[wid*8+5]=s5;
    }
    __syncthreads();
    const float iph = rsqrtf(sred[0]+sred[8] +1e-12f);
    const float ipt = rsqrtf(sred[1]+sred[9] +1e-12f);
    const float inh = rsqrtf(sred[2]+sred[10]+1e-12f);
    const float itn = rsqrtf(sred[3]+sred[11]+1e-12f);
    const float ipr = rsqrtf(sred[4]+sred[12]+1e-12f);
    const float inr = rsqrtf(sred[5]+sred[13]+1e-12f);
    float pterm = fabsf(aph*iph + prr*ipr - apt*ipt);
    float nterm = fabsf(anh*inh + nrr*inr - ant*itn);
    #pragma unroll
    for (int off = 32; off; off >>= 1) {
        pterm += __shfl_xor(pterm, off);
        nterm += __shfl_xor(nterm, off);
    }
    __syncthreads();
    if (lane == 0) { sred[wid*2+0] = pterm; sred[wid*2+1] = nterm; }
    __syncthreads();
    if (r == 0) {
        atomicAdd(out, fmaxf(sred[0]+sred[2] - sred[1]-sred[3] + MARGIN, 0.f) / (float)B);
    }
}

// ---------------- launch ----------------

extern "C" void kernel_launch(void* const* d_in, const int* in_sizes, int n_in,
                              void* d_out, int out_size, void* d_ws, size_t ws_size,
                              hipStream_t stream) {
    const float* ent  = (const float*)d_in[0];
    const float* rel  = (const float*)d_in[1];
    const float* tmat = (const float*)d_in[2];
    const int* pos_h      = (const int*)d_in[3];
    const int* pos_t      = (const int*)d_in[4];
    const int* pos_r      = (const int*)d_in[5];
    const int* pos_type_r = (const int*)d_in[6];
    const int* neg_h      = (const int*)d_in[7];
    const int* neg_t      = (const int*)d_in[8];
    const int* neg_r      = (const int*)d_in[9];
    float* out = (float*)d_out;
    const int B = in_sizes[3];
    const int ntype = in_sizes[2] / (D * D);

    if (ws_size < WS_NEEDED || ntype > MAX_TYPES || B > MAX_B) {
        hipMemsetAsync(out, 0, sizeof(float), stream);
        transr_fallback<<<B, 128, 0, stream>>>(
            ent, rel, tmat, pos_h, pos_t, pos_r, pos_type_r,
            neg_h, neg_t, neg_r, out, B);
        return;
    }

    int* ws = (int*)d_ws;
    group_kernel<<<1, 1024, 0, stream>>>(pos_type_r, ws, out, B, ntype);
    transr_main<<<GRID_MAIN, 256, 0, stream>>>(
        ent, rel, tmat, pos_h, pos_t, pos_r, neg_h, neg_t, neg_r,
        ws, out, 1.0f / (float)B);
}

// Round 4
// 67.802 us; speedup vs baseline: 1.2549x; 1.2549x over previous
//
#include <hip/hip_runtime.h>

#define D 128
#define CHUNK 8
#define MAX_TYPES 1024
#define MAX_B 8192
#define MARGIN 1.0f

// ws layout (int units unless noted)
#define WS_NITEMS 0
#define WS_ORDER  64                     // 8192 ints
#define WS_ITEMS  8448                   // int4 x 2048 (byte 33792, 16B aligned)
#define WS_PROJ_BYTES 131072             // proj floats: 4 roles x B x 128
#define WS_NEEDED ((size_t)WS_PROJ_BYTES + (size_t)4 * MAX_B * D * 4)

// ---------------- fused grouping kernel (1 block, 1024 thr) ----------------

__global__ __launch_bounds__(1024) void group_kernel(
    const int* __restrict__ type_r, int* __restrict__ ws,
    float* __restrict__ out, int B, int ntype)
{
    __shared__ int hist[MAX_TYPES];
    __shared__ int typec[MAX_B];
    __shared__ int wsum[16], wsum2[16];
    const int tid = threadIdx.x;
    const int lane = tid & 63;
    const int wv = tid >> 6;

    if (tid == 0) out[0] = 0.0f;
    hist[tid] = 0;
    __syncthreads();
    for (int i = tid; i < B; i += 1024) {
        const int t = type_r[i];
        typec[i] = t;
        atomicAdd(&hist[t], 1);
    }
    __syncthreads();
    const int c  = (tid < ntype) ? hist[tid] : 0;
    const int ic = (c + CHUNK - 1) / CHUNK;
    // wave-level inclusive scans of c and ic
    int vc = c, vic = ic;
    #pragma unroll
    for (int off = 1; off < 64; off <<= 1) {
        const int tc  = __shfl_up(vc,  off);
        const int tic = __shfl_up(vic, off);
        if (lane >= off) { vc += tc; vic += tic; }
    }
    if (lane == 63) { wsum[wv] = vc; wsum2[wv] = vic; }
    __syncthreads();
    if (wv == 0 && lane < 16) {
        int a = wsum[lane], b = wsum2[lane];
        #pragma unroll
        for (int off = 1; off < 16; off <<= 1) {
            const int ta = __shfl_up(a, off);
            const int tb = __shfl_up(b, off);
            if (lane >= off) { a += ta; b += tb; }
        }
        wsum[lane] = a; wsum2[lane] = b;
    }
    __syncthreads();
    const int base_c  = (wv ? wsum[wv - 1]  : 0) + vc - c;    // exclusive prefix
    const int base_ic = (wv ? wsum2[wv - 1] : 0) + vic - ic;
    hist[tid] = base_c;                   // becomes scatter cursor
    if (tid < ntype && ic > 0) {
        int4* items = (int4*)(ws + WS_ITEMS);
        for (int k = 0; k < ic; ++k)
            items[base_ic + k] = make_int4(tid, base_c + k * CHUNK,
                                           min(CHUNK, c - k * CHUNK), 0);
    }
    if (tid == 0) ws[WS_NITEMS] = wsum2[15];
    __syncthreads();
    for (int i = tid; i < B; i += 1024) {
        const int p = atomicAdd(&hist[typec[i]], 1);
        ws[WS_ORDER + p] = i;
    }
}

// ---------------- projection kernel ----------------
// 256 thr = 4 waves. lane: cg = lane&31 (cols cg*4..+3), hl = lane>>5.
// Wave wq + hl own dims [wq*32 + hl*16, +16). T panel: 16 x float4 = 64 VGPR.

__global__ __launch_bounds__(256, 4) void proj_kernel(
    const float* __restrict__ ent,
    const float* __restrict__ tmat,
    const int* __restrict__ pos_h,
    const int* __restrict__ pos_t,
    const int* __restrict__ neg_h,
    const int* __restrict__ neg_t,
    const int* __restrict__ ws,
    float* __restrict__ proj,
    int B)
{
    const int nit = ws[WS_NITEMS];
    if (blockIdx.x >= nit) return;
    const int4 item = ((const int4*)(ws + WS_ITEMS))[blockIdx.x];
    const int type  = item.x;
    const int start = item.y;
    const int cnt   = item.z;

    const int tid  = threadIdx.x;
    const int lane = tid & 63;
    const int wq   = tid >> 6;
    const int cg   = lane & 31;
    const int hl   = lane >> 5;
    const int rowbase = wq * 32 + hl * 16;

    __shared__ float4 vbuf[2][D];
    __shared__ float  pacc[4 * 32 * 20];   // [wq][cg] slots of 20 floats (16 used)

    // T panel into registers (coalesced float4)
    float4 t4[16];
    {
        const float* Tp = tmat + (size_t)type * (D * D) + (size_t)rowbase * D + cg * 4;
        #pragma unroll
        for (int r = 0; r < 16; ++r)
            t4[r] = *(const float4*)(Tp + r * D);
    }

    const int* ordr = ws + WS_ORDER;

    // stage sample 0
    if (tid < 128) {
        const int i0 = ordr[start];
        float4 v;
        v.x = ent[(size_t)pos_h[i0] * D + tid];
        v.y = ent[(size_t)pos_t[i0] * D + tid];
        v.z = ent[(size_t)neg_h[i0] * D + tid];
        v.w = ent[(size_t)neg_t[i0] * D + tid];
        vbuf[0][tid] = v;
    }
    __syncthreads();

    for (int j = 0; j < cnt; ++j) {
        // stage sample j+1 into other buffer (overlaps compute)
        if (j + 1 < cnt && tid < 128) {
            const int i1 = ordr[start + j + 1];
            float4 v;
            v.x = ent[(size_t)pos_h[i1] * D + tid];
            v.y = ent[(size_t)pos_t[i1] * D + tid];
            v.z = ent[(size_t)neg_h[i1] * D + tid];
            v.w = ent[(size_t)neg_t[i1] * D + tid];
            vbuf[(j + 1) & 1][tid] = v;
        }

        // matvec: acc{i} = col cg*4+i, components = roles {ph,pt,nh,nt}
        const float4* vb = vbuf[j & 1] + rowbase;
        float4 a0 = make_float4(0.f,0.f,0.f,0.f), a1 = a0, a2 = a0, a3 = a0;
        #pragma unroll
        for (int r = 0; r < 16; ++r) {
            const float4 v = vb[r];     // broadcast b128 (2 addrs/wave, free)
            const float4 t = t4[r];
            a0.x = fmaf(t.x, v.x, a0.x); a0.y = fmaf(t.x, v.y, a0.y);
            a0.z = fmaf(t.x, v.z, a0.z); a0.w = fmaf(t.x, v.w, a0.w);
            a1.x = fmaf(t.y, v.x, a1.x); a1.y = fmaf(t.y, v.y, a1.y);
            a1.z = fmaf(t.y, v.z, a1.z); a1.w = fmaf(t.y, v.w, a1.w);
            a2.x = fmaf(t.z, v.x, a2.x); a2.y = fmaf(t.z, v.y, a2.y);
            a2.z = fmaf(t.z, v.z, a2.z); a2.w = fmaf(t.z, v.w, a2.w);
            a3.x = fmaf(t.w, v.x, a3.x); a3.y = fmaf(t.w, v.y, a3.y);
            a3.z = fmaf(t.w, v.z, a3.z); a3.w = fmaf(t.w, v.w, a3.w);
        }
        // combine the two 16-dim halves within the wave
        a0.x += __shfl_xor(a0.x, 32); a0.y += __shfl_xor(a0.y, 32);
        a0.z += __shfl_xor(a0.z, 32); a0.w += __shfl_xor(a0.w, 32);
        a1.x += __shfl_xor(a1.x, 32); a1.y += __shfl_xor(a1.y, 32);
        a1.z += __shfl_xor(a1.z, 32); a1.w += __shfl_xor(a1.w, 32);
        a2.x += __shfl_xor(a2.x, 32); a2.y += __shfl_xor(a2.y, 32);
        a2.z += __shfl_xor(a2.z, 32); a2.w += __shfl_xor(a2.w, 32);
        a3.x += __shfl_xor(a3.x, 32); a3.y += __shfl_xor(a3.y, 32);
        a3.z += __shfl_xor(a3.z, 32); a3.w += __shfl_xor(a3.w, 32);

        if (hl == 0) {
            float* slot = pacc + (wq * 32 + cg) * 20;
            *(float4*)(slot + 0)  = make_float4(a0.x, a1.x, a2.x, a3.x); // role 0
            *(float4*)(slot + 4)  = make_float4(a0.y, a1.y, a2.y, a3.y); // role 1
            *(float4*)(slot + 8)  = make_float4(a0.z, a1.z, a2.z, a3.z); // role 2
            *(float4*)(slot + 12) = make_float4(a0.w, a1.w, a2.w, a3.w); // role 3
        }
        __syncthreads();   // B1: pacc ready

        if (tid < 128) {
            const int cg2 = tid >> 2, i2 = tid & 3;
            const float* s0 = pacc + cg2 * 20 + i2;
            const float* s1 = s0 + 640;
            const float* s2 = s0 + 1280;
            const float* s3 = s0 + 1920;
            const int i_s = ordr[start + j];
            #pragma unroll
            for (int ro = 0; ro < 4; ++ro) {
                const float o = s0[ro * 4] + s1[ro * 4] + s2[ro * 4] + s3[ro * 4];
                proj[((size_t)ro * B + i_s) * D + tid] = o;
            }
        }
        __syncthreads();   // B2: pacc consumed before next overwrite
    }
}

// ---------------- score kernel (wave per sample) ----------------

#define BFLY6(x) { x += __shfl_xor(x, 1); x += __shfl_xor(x, 2); x += __shfl_xor(x, 4); \
                   x += __shfl_xor(x, 8); x += __shfl_xor(x, 16); x += __shfl_xor(x, 32); }

__global__ __launch_bounds__(256) void score_kernel(
    const float* __restrict__ proj,
    const float* __restrict__ rel,
    const int* __restrict__ pos_r,
    const int* __restrict__ neg_r,
    float* __restrict__ out,
    int B, int nwaves, float inv_B)
{
    const int tid = threadIdx.x;
    const int lane = tid & 63;
    const int wv = tid >> 6;
    const int gw = blockIdx.x * 4 + wv;
    __shared__ float sred[4];

    float wl = 0.f;
    for (int s = gw; s < B; s += nwaves) {
        const int d0 = lane, d1 = lane + 64;
        const size_t base = (size_t)s * D;
        const float ph0 = proj[(0 * (size_t)B) * D + base + d0];
        const float ph1 = proj[(0 * (size_t)B) * D + base + d1];
        const float pt0 = proj[(1 * (size_t)B) * D + base + d0];
        const float pt1 = proj[(1 * (size_t)B) * D + base + d1];
        const float nh0 = proj[(2 * (size_t)B) * D + base + d0];
        const float nh1 = proj[(2 * (size_t)B) * D + base + d1];
        const float nt0 = proj[(3 * (size_t)B) * D + base + d0];
        const float nt1 = proj[(3 * (size_t)B) * D + base + d1];
        const int pri = pos_r[s], nri = neg_r[s];
        const float pr0 = rel[(size_t)pri * D + d0], pr1 = rel[(size_t)pri * D + d1];
        const float nr0 = rel[(size_t)nri * D + d0], nr1 = rel[(size_t)nri * D + d1];

        float sph = ph0*ph0 + ph1*ph1;
        float spt = pt0*pt0 + pt1*pt1;
        float snh = nh0*nh0 + nh1*nh1;
        float snt = nt0*nt0 + nt1*nt1;
        float spr = pr0*pr0 + pr1*pr1;
        float snr = nr0*nr0 + nr1*nr1;
        BFLY6(sph); BFLY6(spt); BFLY6(snh); BFLY6(snt); BFLY6(spr); BFLY6(snr);
        const float iph = rsqrtf(sph + 1e-12f);
        const float ipt = rsqrtf(spt + 1e-12f);
        const float inh = rsqrtf(snh + 1e-12f);
        const float itn = rsqrtf(snt + 1e-12f);
        const float ipr = rsqrtf(spr + 1e-12f);
        const float inr = rsqrtf(snr + 1e-12f);

        float z = fabsf(ph0*iph + pr0*ipr - pt0*ipt)
                + fabsf(ph1*iph + pr1*ipr - pt1*ipt)
                - fabsf(nh0*inh + nr0*inr - nt0*itn)
                - fabsf(nh1*inh + nr1*inr - nt1*itn);
        BFLY6(z);
        wl += fmaxf(z + MARGIN, 0.f);
    }
    if (lane == 0) sred[wv] = wl;
    __syncthreads();
    if (tid == 0)
        atomicAdd(out, (sred[0] + sred[1] + sred[2] + sred[3]) * inv_B);
}

// ---------------- fallback (round-1 per-sample kernel) ----------------

__global__ __launch_bounds__(128) void transr_fallback(
    const float* __restrict__ ent, const float* __restrict__ rel,
    const float* __restrict__ tmat,
    const int* __restrict__ pos_h, const int* __restrict__ pos_t,
    const int* __restrict__ pos_r, const int* __restrict__ pos_type_r,
    const int* __restrict__ neg_h, const int* __restrict__ neg_t,
    const int* __restrict__ neg_r, float* __restrict__ out, int B)
{
    const int b = blockIdx.x;
    const int r = threadIdx.x;
    const int lane = r & 63;
    const int wid = r >> 6;
    __shared__ float4 vcomb[D];
    __shared__ float sred[16];
    vcomb[r] = make_float4(ent[(size_t)pos_h[b]*D + r], ent[(size_t)pos_t[b]*D + r],
                           ent[(size_t)neg_h[b]*D + r], ent[(size_t)neg_t[b]*D + r]);
    const float prr = rel[(size_t)pos_r[b] * D + r];
    const float nrr = rel[(size_t)neg_r[b] * D + r];
    __syncthreads();
    const float* __restrict__ T = tmat + (size_t)pos_type_r[b] * (D * D);
    float aph = 0.f, apt = 0.f, anh = 0.f, ant = 0.f;
    #pragma unroll 8
    for (int d = 0; d < D; ++d) {
        const float t = T[d * D + r];
        const float4 v = vcomb[d];
        aph = fmaf(v.x, t, aph); apt = fmaf(v.y, t, apt);
        anh = fmaf(v.z, t, anh); ant = fmaf(v.w, t, ant);
    }
    float s0 = aph*aph, s1 = apt*apt, s2 = anh*anh, s3 = ant*ant;
    float s4 = prr*prr, s5 = nrr*nrr;
    #pragma unroll
    for (int off = 32; off; off >>= 1) {
        s0 += __shfl_xor(s0, off); s1 += __shfl_xor(s1, off);
        s2 += __shfl_xor(s2, off); s3 += __shfl_xor(s3, off);
        s4 += __shfl_xor(s4, off); s5 += __shfl_xor(s5, off);
    }
    if (lane == 0) {
        sred[wid*8+0]=s0; sred[wid*8+1]=s1; sred[wid*8+2]=s2;
        sred[wid*8+3]=s3; sred[wid*8+4]=s4; sred[wid*8+5]=s5;
    }
    __syncthreads();
    const float iph = rsqrtf(sred[0]+sred[8] +1e-12f);
    const float ipt = rsqrtf(sred[1]+sred[9] +1e-12f);
    const float inh = rsqrtf(sred[2]+sred[10]+1e-12f);
    const float itn = rsqrtf(sred[3]+sred[11]+1e-12f);
    const float ipr = rsqrtf(sred[4]+sred[12]+1e-12f);
    const float inr = rsqrtf(sred[5]+sred[13]+1e-12f);
    float pterm = fabsf(aph*iph + prr*ipr - apt*ipt);
    float nterm = fabsf(anh*inh + nrr*inr - ant*itn);
    #pragma unroll
    for (int off = 32; off; off >>= 1) {
        pterm += __shfl_xor(pterm, off);
        nterm += __shfl_xor(nterm, off);
    }
    __syncthreads();
    if (lane == 0) { sred[wid*2+0] = pterm; sred[wid*2+1] = nterm; }
    __syncthreads();
    if (r == 0)
        atomicAdd(out, fmaxf(sred[0]+sred[2] - sred[1]-sred[3] + MARGIN, 0.f) / (float)B);
}

// ---------------- launch ----------------

extern "C" void kernel_launch(void* const* d_in, const int* in_sizes, int n_in,
                              void* d_out, int out_size, void* d_ws, size_t ws_size,
                              hipStream_t stream) {
    const float* ent  = (const float*)d_in[0];
    const float* rel  = (const float*)d_in[1];
    const float* tmat = (const float*)d_in[2];
    const int* pos_h      = (const int*)d_in[3];
    const int* pos_t      = (const int*)d_in[4];
    const int* pos_r      = (const int*)d_in[5];
    const int* pos_type_r = (const int*)d_in[6];
    const int* neg_h      = (const int*)d_in[7];
    const int* neg_t      = (const int*)d_in[8];
    const int* neg_r      = (const int*)d_in[9];
    float* out = (float*)d_out;
    const int B = in_sizes[3];
    const int ntype = in_sizes[2] / (D * D);

    if (ws_size < WS_NEEDED || ntype > MAX_TYPES || B > MAX_B) {
        hipMemsetAsync(out, 0, sizeof(float), stream);
        transr_fallback<<<B, 128, 0, stream>>>(
            ent, rel, tmat, pos_h, pos_t, pos_r, pos_type_r,
            neg_h, neg_t, neg_r, out, B);
        return;
    }

    int* ws = (int*)d_ws;
    float* proj = (float*)((char*)d_ws + WS_PROJ_BYTES);

    group_kernel<<<1, 1024, 0, stream>>>(pos_type_r, ws, out, B, ntype);
    proj_kernel<<<2048, 256, 0, stream>>>(
        ent, tmat, pos_h, pos_t, neg_h, neg_t, ws, proj, B);
    score_kernel<<<256, 256, 0, stream>>>(
        proj, rel, pos_r, neg_r, out, B, 1024, 1.0f / (float)B);
}

// Round 5
// 64.884 us; speedup vs baseline: 1.3114x; 1.0450x over previous
//
#include <hip/hip_runtime.h>

#define D 128
#define CHUNK 8
#define MAX_TYPES 1024
#define MAX_B 8192
#define MARGIN 1.0f

// ws layout (int units unless noted)
#define WS_NITEMS 0
#define WS_ORDER  64                     // B ints (sorted order: slot -> sample idx)
#define WS_ITEMS  8448                   // int4 x <=2048
#define WS_PROJ_BYTES 131072             // byte offset of proj region
#define WS_NEEDED ((size_t)WS_PROJ_BYTES + (size_t)4 * MAX_B * D * 4)

// ---------------- fused grouping kernel (1 block, 1024 thr) ----------------

__global__ __launch_bounds__(1024) void group_kernel(
    const int* __restrict__ type_r, int* __restrict__ ws,
    float* __restrict__ out, int B, int ntype)
{
    __shared__ int hist[MAX_TYPES];
    __shared__ int typec[MAX_B];
    __shared__ int wsum[16], wsum2[16];
    const int tid = threadIdx.x;
    const int lane = tid & 63;
    const int wv = tid >> 6;

    if (tid == 0) out[0] = 0.0f;
    hist[tid] = 0;
    __syncthreads();

    // vectorized histogram (int4)
    const int B4 = B >> 2;
    const int4* t4p = (const int4*)type_r;
    for (int i = tid; i < B4; i += 1024) {
        const int4 t = t4p[i];
        typec[i * 4 + 0] = t.x; atomicAdd(&hist[t.x], 1);
        typec[i * 4 + 1] = t.y; atomicAdd(&hist[t.y], 1);
        typec[i * 4 + 2] = t.z; atomicAdd(&hist[t.z], 1);
        typec[i * 4 + 3] = t.w; atomicAdd(&hist[t.w], 1);
    }
    for (int i = (B4 << 2) + tid; i < B; i += 1024) {
        const int t = type_r[i];
        typec[i] = t;
        atomicAdd(&hist[t], 1);
    }
    __syncthreads();

    const int c  = (tid < ntype) ? hist[tid] : 0;
    const int ic = (c + CHUNK - 1) / CHUNK;
    int vc = c, vic = ic;
    #pragma unroll
    for (int off = 1; off < 64; off <<= 1) {
        const int tc  = __shfl_up(vc,  off);
        const int tic = __shfl_up(vic, off);
        if (lane >= off) { vc += tc; vic += tic; }
    }
    if (lane == 63) { wsum[wv] = vc; wsum2[wv] = vic; }
    __syncthreads();
    if (wv == 0 && lane < 16) {
        int a = wsum[lane], b = wsum2[lane];
        #pragma unroll
        for (int off = 1; off < 16; off <<= 1) {
            const int ta = __shfl_up(a, off);
            const int tb = __shfl_up(b, off);
            if (lane >= off) { a += ta; b += tb; }
        }
        wsum[lane] = a; wsum2[lane] = b;
    }
    __syncthreads();
    const int base_c  = (wv ? wsum[wv - 1]  : 0) + vc - c;
    const int base_ic = (wv ? wsum2[wv - 1] : 0) + vic - ic;
    hist[tid] = base_c;                   // scatter cursor
    if (tid < ntype && ic > 0) {
        int4* items = (int4*)(ws + WS_ITEMS);
        for (int k = 0; k < ic; ++k)
            items[base_ic + k] = make_int4(tid, base_c + k * CHUNK,
                                           min(CHUNK, c - k * CHUNK), 0);
    }
    if (tid == 0) ws[WS_NITEMS] = wsum2[15];
    __syncthreads();
    for (int i = tid; i < B; i += 1024) {
        const int p = atomicAdd(&hist[typec[i]], 1);
        ws[WS_ORDER + p] = i;
    }
}

// ---------------- projection helpers ----------------

__device__ __forceinline__ void matvec_store(
    const float4* __restrict__ vb, const float4 t4[16],
    float* __restrict__ paccP, int wq, int cg, int hl)
{
    float4 a0 = make_float4(0.f, 0.f, 0.f, 0.f), a1 = a0, a2 = a0, a3 = a0;
    #pragma unroll
    for (int r = 0; r < 16; ++r) {
        const float4 v = vb[r];      // 2-addr LDS broadcast (free)
        const float4 t = t4[r];
        a0.x = fmaf(t.x, v.x, a0.x); a0.y = fmaf(t.x, v.y, a0.y);
        a0.z = fmaf(t.x, v.z, a0.z); a0.w = fmaf(t.x, v.w, a0.w);
        a1.x = fmaf(t.y, v.x, a1.x); a1.y = fmaf(t.y, v.y, a1.y);
        a1.z = fmaf(t.y, v.z, a1.z); a1.w = fmaf(t.y, v.w, a1.w);
        a2.x = fmaf(t.z, v.x, a2.x); a2.y = fmaf(t.z, v.y, a2.y);
        a2.z = fmaf(t.z, v.z, a2.z); a2.w = fmaf(t.z, v.w, a2.w);
        a3.x = fmaf(t.w, v.x, a3.x); a3.y = fmaf(t.w, v.y, a3.y);
        a3.z = fmaf(t.w, v.z, a3.z); a3.w = fmaf(t.w, v.w, a3.w);
    }
    a0.x += __shfl_xor(a0.x, 32); a0.y += __shfl_xor(a0.y, 32);
    a0.z += __shfl_xor(a0.z, 32); a0.w += __shfl_xor(a0.w, 32);
    a1.x += __shfl_xor(a1.x, 32); a1.y += __shfl_xor(a1.y, 32);
    a1.z += __shfl_xor(a1.z, 32); a1.w += __shfl_xor(a1.w, 32);
    a2.x += __shfl_xor(a2.x, 32); a2.y += __shfl_xor(a2.y, 32);
    a2.z += __shfl_xor(a2.z, 32); a2.w += __shfl_xor(a2.w, 32);
    a3.x += __shfl_xor(a3.x, 32); a3.y += __shfl_xor(a3.y, 32);
    a3.z += __shfl_xor(a3.z, 32); a3.w += __shfl_xor(a3.w, 32);
    if (hl == 0) {
        float* slot = paccP + (wq * 32 + cg) * 20;
        *(float4*)(slot + 0)  = make_float4(a0.x, a1.x, a2.x, a3.x);
        *(float4*)(slot + 4)  = make_float4(a0.y, a1.y, a2.y, a3.y);
        *(float4*)(slot + 8)  = make_float4(a0.z, a1.z, a2.z, a3.z);
        *(float4*)(slot + 12) = make_float4(a0.w, a1.w, a2.w, a3.w);
    }
}

__device__ __forceinline__ void combine_store(
    const float* __restrict__ paccP, float* __restrict__ proj,
    size_t pB, int slotIdx, int tid)
{
    const int cg2 = tid >> 2, i2 = tid & 3;
    const float* s0 = paccP + cg2 * 20 + i2;
    const float* s1 = s0 + 640;
    const float* s2 = s0 + 1280;
    const float* s3 = s0 + 1920;
    const size_t base = (size_t)slotIdx * D + tid;
    #pragma unroll
    for (int ro = 0; ro < 4; ++ro)
        proj[ro * pB + base] = s0[ro * 4] + s1[ro * 4] + s2[ro * 4] + s3[ro * 4];
}

// one pipelined iteration: P = j&1 (static), RVC = reg slot !P, IU = idx slot !P,
// IL = idx slot P. Commits rows j+1, issues rows j+3, computes sample j.
#define PROJ_BODY(J, P, RVC, IU, IL)                                         \
    do {                                                                     \
        if ((J) + 1 < cnt && ldr) vbuf[!(P)][tid] = RVC;                     \
        if ((J) + 4 < cnt) {                                                 \
            const int o_ = ordr[start + (J) + 4];                            \
            IL = make_int4(pos_h[o_], pos_t[o_], neg_h[o_], neg_t[o_]);      \
        }                                                                    \
        if ((J) + 3 < cnt && ldr) {                                          \
            RVC.x = ent[(size_t)IU.x * D + tid];                             \
            RVC.y = ent[(size_t)IU.y * D + tid];                             \
            RVC.z = ent[(size_t)IU.z * D + tid];                             \
            RVC.w = ent[(size_t)IU.w * D + tid];                             \
        }                                                                    \
        matvec_store(vbuf[(P)] + rowbase, t4, pacc[(P)], wq, cg, hl);        \
        __syncthreads();                                                     \
        if (ldr) combine_store(pacc[(P)], proj, pB, start + (J), tid);       \
    } while (0)

// ---------------- projection kernel ----------------

__global__ __launch_bounds__(256, 3) void proj_kernel(
    const float* __restrict__ ent,
    const float* __restrict__ tmat,
    const int* __restrict__ pos_h,
    const int* __restrict__ pos_t,
    const int* __restrict__ neg_h,
    const int* __restrict__ neg_t,
    const int* __restrict__ ws,
    float* __restrict__ proj,
    int B)
{
    const int nit = ws[WS_NITEMS];
    if (blockIdx.x >= nit) return;
    const int4 item = ((const int4*)(ws + WS_ITEMS))[blockIdx.x];
    const int type  = item.x;
    const int start = item.y;
    const int cnt   = item.z;

    const int tid  = threadIdx.x;
    const int lane = tid & 63;
    const int wq   = tid >> 6;
    const int cg   = lane & 31;
    const int hl   = lane >> 5;
    const int rowbase = wq * 32 + hl * 16;
    const bool ldr = (tid < 128);
    const size_t pB = (size_t)B * D;

    __shared__ float4 vbuf[2][D];
    __shared__ float  pacc[2][4 * 32 * 20];

    float4 t4[16];
    {
        const float* Tp = tmat + (size_t)type * (D * D) + (size_t)rowbase * D + cg * 4;
        #pragma unroll
        for (int r = 0; r < 16; ++r)
            t4[r] = *(const float4*)(Tp + r * D);
    }

    const int* ordr = ws + WS_ORDER;

    // prologue: commit rows0; issue rows1 (rv1), rows2 (rv0); idx3 (is1)
    float4 rv0 = make_float4(0.f,0.f,0.f,0.f), rv1 = rv0;
    int4 is0 = make_int4(0,0,0,0), is1 = is0;
    if (ldr) {
        const int o = ordr[start];
        float4 v;
        v.x = ent[(size_t)pos_h[o] * D + tid];
        v.y = ent[(size_t)pos_t[o] * D + tid];
        v.z = ent[(size_t)neg_h[o] * D + tid];
        v.w = ent[(size_t)neg_t[o] * D + tid];
        vbuf[0][tid] = v;
    }
    if (cnt > 1 && ldr) {
        const int o = ordr[start + 1];
        rv1.x = ent[(size_t)pos_h[o] * D + tid];
        rv1.y = ent[(size_t)pos_t[o] * D + tid];
        rv1.z = ent[(size_t)neg_h[o] * D + tid];
        rv1.w = ent[(size_t)neg_t[o] * D + tid];
    }
    if (cnt > 2 && ldr) {
        const int o = ordr[start + 2];
        rv0.x = ent[(size_t)pos_h[o] * D + tid];
        rv0.y = ent[(size_t)pos_t[o] * D + tid];
        rv0.z = ent[(size_t)neg_h[o] * D + tid];
        rv0.w = ent[(size_t)neg_t[o] * D + tid];
    }
    if (cnt > 3) {
        const int o = ordr[start + 3];
        is1 = make_int4(pos_h[o], pos_t[o], neg_h[o], neg_t[o]);
    }
    __syncthreads();   // vbuf[0] visible

    int j = 0;
    while (true) {
        PROJ_BODY(j, 0, rv1, is1, is0);
        if (++j >= cnt) break;
        PROJ_BODY(j, 1, rv0, is0, is1);
        if (++j >= cnt) break;
    }
}

// ---------------- score kernel (slot-ordered, prefetched) ----------------

#define BFLY6(x) { x += __shfl_xor(x, 1); x += __shfl_xor(x, 2); x += __shfl_xor(x, 4); \
                   x += __shfl_xor(x, 8); x += __shfl_xor(x, 16); x += __shfl_xor(x, 32); }

#define SCORE_LOAD(PRE, S)                                                    \
    do {                                                                      \
        const int slot_ = (S);                                                \
        const int is_  = ordr[slot_];                                         \
        const int pri_ = pos_r[is_], nri_ = neg_r[is_];                       \
        const size_t b_ = (size_t)slot_ * D + lane;                           \
        PRE##ph0 = proj[0 * pB + b_]; PRE##ph1 = proj[0 * pB + b_ + 64];      \
        PRE##pt0 = proj[1 * pB + b_]; PRE##pt1 = proj[1 * pB + b_ + 64];      \
        PRE##nh0 = proj[2 * pB + b_]; PRE##nh1 = proj[2 * pB + b_ + 64];      \
        PRE##nt0 = proj[3 * pB + b_]; PRE##nt1 = proj[3 * pB + b_ + 64];      \
        PRE##pr0 = rel[(size_t)pri_ * D + lane];                              \
        PRE##pr1 = rel[(size_t)pri_ * D + lane + 64];                         \
        PRE##nr0 = rel[(size_t)nri_ * D + lane];                              \
        PRE##nr1 = rel[(size_t)nri_ * D + lane + 64];                         \
    } while (0)

__global__ __launch_bounds__(256) void score_kernel(
    const float* __restrict__ proj,
    const float* __restrict__ rel,
    const int* __restrict__ ws,
    const int* __restrict__ pos_r,
    const int* __restrict__ neg_r,
    float* __restrict__ out,
    int B, float inv_B)
{
    const int tid = threadIdx.x;
    const int lane = tid & 63;
    const int wv = tid >> 6;
    const int NW = gridDim.x * 4;
    const int gw = blockIdx.x * 4 + wv;
    const int* ordr = ws + WS_ORDER;
    const size_t pB = (size_t)B * D;
    __shared__ float sred[4];

    float wl = 0.f;
    float cph0=0,cph1=0,cpt0=0,cpt1=0,cnh0=0,cnh1=0,cnt0=0,cnt1=0,
          cpr0=0,cpr1=0,cnr0=0,cnr1=0;
    if (gw < B) SCORE_LOAD(c, gw);

    for (int s = gw; s < B; s += NW) {
        float nph0=0,nph1=0,npt0=0,npt1=0,nnh0=0,nnh1=0,nnt0=0,nnt1=0,
              npr0=0,npr1=0,nnr0=0,nnr1=0;
        const int sn = s + NW;
        if (sn < B) SCORE_LOAD(n, sn);

        float sph = cph0*cph0 + cph1*cph1;
        float spt = cpt0*cpt0 + cpt1*cpt1;
        float snh = cnh0*cnh0 + cnh1*cnh1;
        float snt = cnt0*cnt0 + cnt1*cnt1;
        float spr = cpr0*cpr0 + cpr1*cpr1;
        float snr = cnr0*cnr0 + cnr1*cnr1;
        BFLY6(sph); BFLY6(spt); BFLY6(snh); BFLY6(snt); BFLY6(spr); BFLY6(snr);
        const float iph = rsqrtf(sph + 1e-12f);
        const float ipt = rsqrtf(spt + 1e-12f);
        const float inh = rsqrtf(snh + 1e-12f);
        const float itn = rsqrtf(snt + 1e-12f);
        const float ipr = rsqrtf(spr + 1e-12f);
        const float inr = rsqrtf(snr + 1e-12f);
        float z = fabsf(cph0*iph + cpr0*ipr - cpt0*ipt)
                + fabsf(cph1*iph + cpr1*ipr - cpt1*ipt)
                - fabsf(cnh0*inh + cnr0*inr - cnt0*itn)
                - fabsf(cnh1*inh + cnr1*inr - cnt1*itn);
        BFLY6(z);
        wl += fmaxf(z + MARGIN, 0.f);

        cph0=nph0; cph1=nph1; cpt0=npt0; cpt1=npt1;
        cnh0=nnh0; cnh1=nnh1; cnt0=nnt0; cnt1=nnt1;
        cpr0=npr0; cpr1=npr1; cnr0=nnr0; cnr1=nnr1;
    }
    if (lane == 0) sred[wv] = wl;
    __syncthreads();
    if (tid == 0)
        atomicAdd(out, (sred[0] + sred[1] + sred[2] + sred[3]) * inv_B);
}

// ---------------- fallback (round-1 per-sample kernel) ----------------

__global__ __launch_bounds__(128) void transr_fallback(
    const float* __restrict__ ent, const float* __restrict__ rel,
    const float* __restrict__ tmat,
    const int* __restrict__ pos_h, const int* __restrict__ pos_t,
    const int* __restrict__ pos_r, const int* __restrict__ pos_type_r,
    const int* __restrict__ neg_h, const int* __restrict__ neg_t,
    const int* __restrict__ neg_r, float* __restrict__ out, int B)
{
    const int b = blockIdx.x;
    const int r = threadIdx.x;
    const int lane = r & 63;
    const int wid = r >> 6;
    __shared__ float4 vcomb[D];
    __shared__ float sred[16];
    vcomb[r] = make_float4(ent[(size_t)pos_h[b]*D + r], ent[(size_t)pos_t[b]*D + r],
                           ent[(size_t)neg_h[b]*D + r], ent[(size_t)neg_t[b]*D + r]);
    const float prr = rel[(size_t)pos_r[b] * D + r];
    const float nrr = rel[(size_t)neg_r[b] * D + r];
    __syncthreads();
    const float* __restrict__ T = tmat + (size_t)pos_type_r[b] * (D * D);
    float aph = 0.f, apt = 0.f, anh = 0.f, ant = 0.f;
    #pragma unroll 8
    for (int d = 0; d < D; ++d) {
        const float t = T[d * D + r];
        const float4 v = vcomb[d];
        aph = fmaf(v.x, t, aph); apt = fmaf(v.y, t, apt);
        anh = fmaf(v.z, t, anh); ant = fmaf(v.w, t, ant);
    }
    float s0 = aph*aph, s1 = apt*apt, s2 = anh*anh, s3 = ant*ant;
    float s4 = prr*prr, s5 = nrr*nrr;
    #pragma unroll
    for (int off = 32; off; off >>= 1) {
        s0 += __shfl_xor(s0, off); s1 += __shfl_xor(s1, off);
        s2 += __shfl_xor(s2, off); s3 += __shfl_xor(s3, off);
        s4 += __shfl_xor(s4, off); s5 += __shfl_xor(s5, off);
    }
    if (lane == 0) {
        sred[wid*8+0]=s0; sred[wid*8+1]=s1; sred[wid*8+2]=s2;
        sred[wid*8+3]=s3; sred[wid*8+4]=s4; sred[wid*8+5]=s5;
    }
    __syncthreads();
    const float iph = rsqrtf(sred[0]+sred[8] +1e-12f);
    const float ipt = rsqrtf(sred[1]+sred[9] +1e-12f);
    const float inh = rsqrtf(sred[2]+sred[10]+1e-12f);
    const float itn = rsqrtf(sred[3]+sred[11]+1e-12f);
    const float ipr = rsqrtf(sred[4]+sred[12]+1e-12f);
    const float inr = rsqrtf(sred[5]+sred[13]+1e-12f);
    float pterm = fabsf(aph*iph + prr*ipr - apt*ipt);
    float nterm = fabsf(anh*inh + nrr*inr - ant*itn);
    #pragma unroll
    for (int off = 32; off; off >>= 1) {
        pterm += __shfl_xor(pterm, off);
        nterm += __shfl_xor(nterm, off);
    }
    __syncthreads();
    if (lane == 0) { sred[wid*2+0] = pterm; sred[wid*2+1] = nterm; }
    __syncthreads();
    if (r == 0)
        atomicAdd(out, fmaxf(sred[0]+sred[2] - sred[1]-sred[3] + MARGIN, 0.f) / (float)B);
}

// ---------------- launch ----------------

extern "C" void kernel_launch(void* const* d_in, const int* in_sizes, int n_in,
                              void* d_out, int out_size, void* d_ws, size_t ws_size,
                              hipStream_t stream) {
    const float* ent  = (const float*)d_in[0];
    const float* rel  = (const float*)d_in[1];
    const float* tmat = (const float*)d_in[2];
    const int* pos_h      = (const int*)d_in[3];
    const int* pos_t      = (const int*)d_in[4];
    const int* pos_r      = (const int*)d_in[5];
    const int* pos_type_r = (const int*)d_in[6];
    const int* neg_h      = (const int*)d_in[7];
    const int* neg_t      = (const int*)d_in[8];
    const int* neg_r      = (const int*)d_in[9];
    float* out = (float*)d_out;
    const int B = in_sizes[3];
    const int ntype = in_sizes[2] / (D * D);

    if (ws_size < WS_NEEDED || ntype > MAX_TYPES || B > MAX_B) {
        hipMemsetAsync(out, 0, sizeof(float), stream);
        transr_fallback<<<B, 128, 0, stream>>>(
            ent, rel, tmat, pos_h, pos_t, pos_r, pos_type_r,
            neg_h, neg_t, neg_r, out, B);
        return;
    }

    int* ws = (int*)d_ws;
    float* proj = (float*)((char*)d_ws + WS_PROJ_BYTES);

    group_kernel<<<1, 1024, 0, stream>>>(pos_type_r, ws, out, B, ntype);
    proj_kernel<<<2048, 256, 0, stream>>>(
        ent, tmat, pos_h, pos_t, neg_h, neg_t, ws, proj, B);
    score_kernel<<<512, 256, 0, stream>>>(
        proj, rel, ws, pos_r, neg_r, out, B, 1.0f / (float)B);
}